// Round 4
// baseline (1847.085 us; speedup 1.0000x reference)
//
#include <hip/hip_runtime.h>

// GCN forward via bucketed CSR build + gather aggregation (no float atomics).
//   Phase A: bin edges by dst/NPB into 256 buckets (packed (loc<<20)|src).
//   Phase B: per-bucket LDS histogram+scan -> counts/offs/dinv + CSR placement
//            into a contiguous 50KB span (L2-resident, full-line writes).
//   gemm1: xwd = (x@W1)*dinv;  agg1[d] = dinv[d]*(xwd[d]+sum_in xwd[s]);
//   gemm2: h2wd = (relu(agg1+b1)@W2)*dinv;  agg2 likewise;  head.

#define TPB 256
#define NBUCK 256
#define BCAP 16384  // bucket capacity; mean ~12512, sigma ~112 -> huge margin

__global__ void zero_bcursor_kernel(int* __restrict__ bcur) {
    bcur[threadIdx.x] = 0;
}

// Phase A: scatter edges into per-bucket staging (packed u32)
__global__ void binA_kernel(const int* __restrict__ src, const int* __restrict__ dst,
                            int* __restrict__ bcur, unsigned* __restrict__ staging,
                            int E, int NPB) {
    int e = blockIdx.x * blockDim.x + threadIdx.x;
    if (e >= E) return;
    int s = src[e], d = dst[e];
    int b = d / NPB;
    int loc = d - b * NPB;
    int pos = atomicAdd(&bcur[b], 1);
    if (pos < BCAP)  // defensive; never hit for uniform input
        staging[(size_t)b * BCAP + pos] = ((unsigned)loc << 20) | (unsigned)s;
}

// Exclusive scan of clamped bucket sizes -> bbase (single block of 256)
__global__ void bucket_scan_kernel(const int* __restrict__ bcur, int* __restrict__ bbase) {
    __shared__ int s[NBUCK];
    int tid = threadIdx.x;
    int v = min(bcur[tid], BCAP);
    s[tid] = v;
    __syncthreads();
    for (int d = 1; d < NBUCK; d <<= 1) {
        int t = 0;
        if (tid >= d) t = s[tid - d];
        __syncthreads();
        s[tid] += t;
        __syncthreads();
    }
    bbase[tid] = s[tid] - v;  // exclusive
}

// Phase B: one block (512 thr) per bucket. Histogram + scan + CSR placement.
__global__ void buildB_kernel(const int* __restrict__ bcur, const int* __restrict__ bbase,
                              const unsigned* __restrict__ staging,
                              int* __restrict__ offs, int* __restrict__ counts,
                              float* __restrict__ dinv, int* __restrict__ csr_src,
                              int N, int NPB) {
    __shared__ int hist[512];
    __shared__ int scan_[512];
    __shared__ int cur[512];
    int b = blockIdx.x;
    int tid = threadIdx.x;
    int sz = min(bcur[b], BCAP);
    int base = bbase[b];
    int n0 = b * NPB;
    int nn = min(NPB, N - n0);
    const unsigned* se = staging + (size_t)b * BCAP;

    hist[tid] = 0;
    __syncthreads();
    for (int i = tid; i < sz; i += 512)
        atomicAdd(&hist[se[i] >> 20], 1);
    __syncthreads();
    int h = hist[tid];
    scan_[tid] = h;
    __syncthreads();
    for (int d = 1; d < 512; d <<= 1) {
        int t = 0;
        if (tid >= d) t = scan_[tid - d];
        __syncthreads();
        scan_[tid] += t;
        __syncthreads();
    }
    int excl = scan_[tid] - h;
    cur[tid] = excl;
    if (tid < nn) {
        int node = n0 + tid;
        offs[node] = base + excl;
        counts[node] = h;
        dinv[node] = rsqrtf((float)(h + 1));  // +1 self-loop
    }
    __syncthreads();
    for (int i = tid; i < sz; i += 512) {
        unsigned p = se[i];
        int pos = atomicAdd(&cur[p >> 20], 1);
        csr_src[base + pos] = (int)(p & 0xFFFFFu);
    }
}

// xwd = (x @ W1) * dinv[node]
__global__ void gemm1_kernel(const float* __restrict__ x, const float* __restrict__ W1,
                             const float* __restrict__ dinv, float* __restrict__ xwd, int N) {
    __shared__ float ws_[128 * 32];
    for (int i = threadIdx.x; i < 128 * 32; i += blockDim.x) ws_[i] = W1[i];
    __syncthreads();
    int node = blockIdx.x * blockDim.x + threadIdx.x;
    if (node >= N) return;
    float acc[32];
#pragma unroll
    for (int j = 0; j < 32; ++j) acc[j] = 0.0f;
    const float4* xr = (const float4*)(x + (size_t)node * 128);
#pragma unroll 4
    for (int k4 = 0; k4 < 32; ++k4) {
        float4 xv = xr[k4];
        const float* wk = ws_ + k4 * 128;
#pragma unroll
        for (int j4 = 0; j4 < 8; ++j4) {
            float4 w0 = *(const float4*)(wk + j4 * 4);
            float4 w1 = *(const float4*)(wk + 32 + j4 * 4);
            float4 w2 = *(const float4*)(wk + 64 + j4 * 4);
            float4 w3 = *(const float4*)(wk + 96 + j4 * 4);
            acc[j4 * 4 + 0] += xv.x * w0.x + xv.y * w1.x + xv.z * w2.x + xv.w * w3.x;
            acc[j4 * 4 + 1] += xv.x * w0.y + xv.y * w1.y + xv.z * w2.y + xv.w * w3.y;
            acc[j4 * 4 + 2] += xv.x * w0.z + xv.y * w1.z + xv.z * w2.z + xv.w * w3.z;
            acc[j4 * 4 + 3] += xv.x * w0.w + xv.y * w1.w + xv.z * w2.w + xv.w * w3.w;
        }
    }
    float d = dinv[node];
    float4* xp = (float4*)(xwd + (size_t)node * 32);
#pragma unroll
    for (int j4 = 0; j4 < 8; ++j4)
        xp[j4] = make_float4(acc[j4 * 4 + 0] * d, acc[j4 * 4 + 1] * d,
                             acc[j4 * 4 + 2] * d, acc[j4 * 4 + 3] * d);
}

// One wave per node: agg1[d] = dinv[d] * (xwd[d] + sum_{s in in(d)} xwd[s])
__global__ void agg32_kernel(const int* __restrict__ offs, const int* __restrict__ counts,
                             const int* __restrict__ csr_src, const float* __restrict__ dinv,
                             const float* __restrict__ xwd, float* __restrict__ agg, int N) {
    int wave = threadIdx.x >> 6;
    int lane = threadIdx.x & 63;
    int node = blockIdx.x * 4 + wave;
    if (node >= N) return;
    int f = lane & 31;
    int j = lane >> 5;  // 0..1 : two edges in flight per wave
    int off = offs[node];
    int deg = counts[node];
    float acc = (j == 0) ? xwd[(size_t)node * 32 + f] : 0.0f;
    for (int i = j; i < deg; i += 2) {
        int s = csr_src[off + i];
        acc += xwd[(size_t)s * 32 + f];
    }
    acc += __shfl_down(acc, 32, 64);
    if (j == 0) agg[(size_t)node * 32 + f] = acc * dinv[node];
}

// h2wd = (relu(agg1 + b1) @ W2) * dinv[node]
__global__ void gemm2_kernel(const float* __restrict__ agg1, const float* __restrict__ W2,
                             const float* __restrict__ b1, const float* __restrict__ dinv,
                             float* __restrict__ h2wd, int N) {
    __shared__ float ws_[32 * 16];
    __shared__ float bs_[32];
    for (int i = threadIdx.x; i < 32 * 16; i += blockDim.x) ws_[i] = W2[i];
    if (threadIdx.x < 32) bs_[threadIdx.x] = b1[threadIdx.x];
    __syncthreads();
    int node = blockIdx.x * blockDim.x + threadIdx.x;
    if (node >= N) return;
    float h[32];
    const float4* ar = (const float4*)(agg1 + (size_t)node * 32);
#pragma unroll
    for (int k4 = 0; k4 < 8; ++k4) {
        float4 v = ar[k4];
        h[k4 * 4 + 0] = fmaxf(v.x + bs_[k4 * 4 + 0], 0.0f);
        h[k4 * 4 + 1] = fmaxf(v.y + bs_[k4 * 4 + 1], 0.0f);
        h[k4 * 4 + 2] = fmaxf(v.z + bs_[k4 * 4 + 2], 0.0f);
        h[k4 * 4 + 3] = fmaxf(v.w + bs_[k4 * 4 + 3], 0.0f);
    }
    float acc[16];
#pragma unroll
    for (int j = 0; j < 16; ++j) acc[j] = 0.0f;
#pragma unroll
    for (int k = 0; k < 32; ++k) {
        float hv = h[k];
#pragma unroll
        for (int j4 = 0; j4 < 4; ++j4) {
            float4 w = *(const float4*)(ws_ + k * 16 + j4 * 4);
            acc[j4 * 4 + 0] += hv * w.x;
            acc[j4 * 4 + 1] += hv * w.y;
            acc[j4 * 4 + 2] += hv * w.z;
            acc[j4 * 4 + 3] += hv * w.w;
        }
    }
    float d = dinv[node];
    float4* hp = (float4*)(h2wd + (size_t)node * 16);
#pragma unroll
    for (int j4 = 0; j4 < 4; ++j4)
        hp[j4] = make_float4(acc[j4 * 4 + 0] * d, acc[j4 * 4 + 1] * d,
                             acc[j4 * 4 + 2] * d, acc[j4 * 4 + 3] * d);
}

// One wave per node, 16 feats
__global__ void agg16_kernel(const int* __restrict__ offs, const int* __restrict__ counts,
                             const int* __restrict__ csr_src, const float* __restrict__ dinv,
                             const float* __restrict__ h2wd, float* __restrict__ agg, int N) {
    int wave = threadIdx.x >> 6;
    int lane = threadIdx.x & 63;
    int node = blockIdx.x * 4 + wave;
    if (node >= N) return;
    int f = lane & 15;
    int j = lane >> 4;  // 0..3 : four edges in flight per wave
    int off = offs[node];
    int deg = counts[node];
    float acc = (j == 0) ? h2wd[(size_t)node * 16 + f] : 0.0f;
    for (int i = j; i < deg; i += 4) {
        int s = csr_src[off + i];
        acc += h2wd[(size_t)s * 16 + f];
    }
    acc += __shfl_down(acc, 32, 64);
    acc += __shfl_down(acc, 16, 64);
    if (j == 0) agg[(size_t)node * 16 + f] = acc * dinv[node];
}

// out = relu(agg2 + b2) @ Wf + bf
__global__ void final_kernel(const float* __restrict__ agg2, const float* __restrict__ b2,
                             const float* __restrict__ Wf, const float* __restrict__ bf,
                             float* __restrict__ out, int N) {
    int i = blockIdx.x * blockDim.x + threadIdx.x;
    if (i >= N) return;
    const float4* ar = (const float4*)(agg2 + (size_t)i * 16);
    float acc = bf[0];
#pragma unroll
    for (int j4 = 0; j4 < 4; ++j4) {
        float4 v = ar[j4];
        acc += fmaxf(v.x + b2[j4 * 4 + 0], 0.0f) * Wf[j4 * 4 + 0];
        acc += fmaxf(v.y + b2[j4 * 4 + 1], 0.0f) * Wf[j4 * 4 + 1];
        acc += fmaxf(v.z + b2[j4 * 4 + 2], 0.0f) * Wf[j4 * 4 + 2];
        acc += fmaxf(v.w + b2[j4 * 4 + 3], 0.0f) * Wf[j4 * 4 + 3];
    }
    out[i] = acc;
}

extern "C" void kernel_launch(void* const* d_in, const int* in_sizes, int n_in,
                              void* d_out, int out_size, void* d_ws, size_t ws_size,
                              hipStream_t stream) {
    const float* x  = (const float*)d_in[0];
    const int*   ei = (const int*)d_in[1];
    const float* W1 = (const float*)d_in[2];
    const float* b1 = (const float*)d_in[3];
    const float* W2 = (const float*)d_in[4];
    const float* b2 = (const float*)d_in[5];
    const float* Wf = (const float*)d_in[6];
    const float* bf = (const float*)d_in[7];

    int N = in_sizes[0] / 128;
    int E = in_sizes[1] / 2;
    const int* src = ei;       // edge_index[0]
    const int* dst = ei + E;   // edge_index[1]
    int NPB = (N + NBUCK - 1) / NBUCK;  // nodes per bucket (391 for N=100k; <512)

    // Workspace layout
    size_t Np = ((size_t)N + 3) & ~(size_t)3;
    size_t Ep = ((size_t)E + 3) & ~(size_t)3;
    int* wsI      = (int*)d_ws;
    int* counts   = wsI;               // N
    int* offs     = counts + Np;       // N
    int* bcur     = offs + Np;         // 256
    int* bbase    = bcur + NBUCK;      // 256
    int* csr_src  = bbase + NBUCK;     // E
    float* dinv   = (float*)(csr_src + Ep);   // N
    float* xwd    = dinv + Np;         // 32*N
    float* agg1   = xwd + 32 * Np;     // 32*N
    float* h2wd   = agg1 + 32 * Np;    // 16*N
    float* agg2   = h2wd + 16 * Np;    // 16*N
    float* out    = (float*)d_out;
    // Staging (16 MB) aliases agg1+h2wd (19.2 MB): last read in buildB_kernel,
    // first overwritten later by agg32_kernel. No overlap in lifetime.
    unsigned* staging = (unsigned*)agg1;

    int nbN = (N + TPB - 1) / TPB;
    int nbE = (E + TPB - 1) / TPB;
    int nbW = (N + 3) / 4;  // one wave (of 4/block) per node

    zero_bcursor_kernel<<<1, NBUCK, 0, stream>>>(bcur);
    binA_kernel<<<nbE, TPB, 0, stream>>>(src, dst, bcur, staging, E, NPB);
    bucket_scan_kernel<<<1, NBUCK, 0, stream>>>(bcur, bbase);
    buildB_kernel<<<NBUCK, 512, 0, stream>>>(bcur, bbase, staging, offs, counts,
                                             dinv, csr_src, N, NPB);
    gemm1_kernel<<<nbN, TPB, 0, stream>>>(x, W1, dinv, xwd, N);
    agg32_kernel<<<nbW, TPB, 0, stream>>>(offs, counts, csr_src, dinv, xwd, agg1, N);
    gemm2_kernel<<<nbN, TPB, 0, stream>>>(agg1, W2, b1, dinv, h2wd, N);
    agg16_kernel<<<nbW, TPB, 0, stream>>>(offs, counts, csr_src, dinv, h2wd, agg2, N);
    final_kernel<<<nbN, TPB, 0, stream>>>(agg2, b2, Wf, bf, out, N);
}

// Round 5
// 425.658 us; speedup vs baseline: 4.3394x; 4.3394x over previous
//
#include <hip/hip_runtime.h>

// GCN forward via two-level CSR build + gather aggregation (no float atomics).
//   Phase A (binA2): per-block LDS radix partition of 8192 edges into 256
//     dst-range buckets; one global atomicAdd per (block,bucket) reserves
//     staging space; sorted LDS flush -> near-coalesced staging writes.
//   Phase B (buildB): one block per bucket: LDS histogram+scan -> counts/offs/
//     dinv + CSR placement into contiguous span (L2-resident full-line writes).
//   gemm1: xwd = (x@W1)*dinv;  agg1[d] = dinv[d]*(xwd[d]+sum_in xwd[s]);
//   gemm2: h2wd = (relu(agg1+b1)@W2)*dinv;  agg2 likewise;  head.

#define TPB 256
#define NBUCK 256
#define BCAP 16384   // bucket capacity; mean ~12512 -> large margin
#define CHUNK 8192   // edges per binA2 block

__global__ void zero_bcursor_kernel(int* __restrict__ bcur) {
    bcur[threadIdx.x] = 0;
}

// Phase A: block-local radix partition, then bulk append to global staging.
__global__ __launch_bounds__(256) void binA2_kernel(
        const int* __restrict__ src, const int* __restrict__ dst,
        int* __restrict__ bcur, unsigned* __restrict__ staging, int E, int NPB) {
    __shared__ unsigned packed[CHUNK];
    __shared__ unsigned char buckb[CHUNK];
    __shared__ int hist[NBUCK];
    __shared__ int scan_[NBUCK];
    __shared__ int lstart[NBUCK];
    __shared__ int lcur[NBUCK];
    __shared__ int gbase[NBUCK];
    int tid = threadIdx.x;
    int start = blockIdx.x * CHUNK;
    int sz = min(CHUNK, E - start);

    hist[tid] = 0;
    __syncthreads();
    for (int i = tid; i < sz; i += 256) {
        unsigned d = (unsigned)dst[start + i];
        atomicAdd(&hist[d / (unsigned)NPB], 1);
    }
    __syncthreads();
    // exclusive scan of hist (256 entries, 256 threads)
    int v = hist[tid];
    scan_[tid] = v;
    __syncthreads();
    for (int dd = 1; dd < NBUCK; dd <<= 1) {
        int t = 0;
        if (tid >= dd) t = scan_[tid - dd];
        __syncthreads();
        scan_[tid] += t;
        __syncthreads();
    }
    lstart[tid] = scan_[tid] - v;
    lcur[tid] = 0;
    gbase[tid] = atomicAdd(&bcur[tid], v);  // reserve once per (block,bucket)
    __syncthreads();
    // place edges into LDS sorted by bucket
    for (int i = tid; i < sz; i += 256) {
        unsigned d = (unsigned)dst[start + i];
        unsigned s = (unsigned)src[start + i];
        unsigned b = d / (unsigned)NPB;
        unsigned loc = d - b * (unsigned)NPB;
        int pos = atomicAdd(&lcur[b], 1);
        int si = lstart[b] + pos;
        packed[si] = (loc << 20) | s;
        buckb[si] = (unsigned char)b;
    }
    __syncthreads();
    // flush: consecutive tid -> consecutive staging addresses within runs
    for (int i = tid; i < sz; i += 256) {
        unsigned b = buckb[i];
        int dsti = gbase[b] + (i - lstart[b]);
        if (dsti < BCAP)
            staging[(size_t)b * BCAP + dsti] = packed[i];
    }
}

// Exclusive scan of clamped bucket sizes -> bbase (single block of 256)
__global__ void bucket_scan_kernel(const int* __restrict__ bcur, int* __restrict__ bbase) {
    __shared__ int s[NBUCK];
    int tid = threadIdx.x;
    int v = min(bcur[tid], BCAP);
    s[tid] = v;
    __syncthreads();
    for (int d = 1; d < NBUCK; d <<= 1) {
        int t = 0;
        if (tid >= d) t = s[tid - d];
        __syncthreads();
        s[tid] += t;
        __syncthreads();
    }
    bbase[tid] = s[tid] - v;  // exclusive
}

// Phase B: one block (512 thr) per bucket. Histogram + scan + CSR placement.
__global__ void buildB_kernel(const int* __restrict__ bcur, const int* __restrict__ bbase,
                              const unsigned* __restrict__ staging,
                              int* __restrict__ offs, int* __restrict__ counts,
                              float* __restrict__ dinv, int* __restrict__ csr_src,
                              int N, int NPB) {
    __shared__ int hist[512];
    __shared__ int scan_[512];
    __shared__ int cur[512];
    int b = blockIdx.x;
    int tid = threadIdx.x;
    int sz = min(bcur[b], BCAP);
    int base = bbase[b];
    int n0 = b * NPB;
    int nn = min(NPB, N - n0);
    const unsigned* se = staging + (size_t)b * BCAP;

    hist[tid] = 0;
    __syncthreads();
    for (int i = tid; i < sz; i += 512)
        atomicAdd(&hist[se[i] >> 20], 1);
    __syncthreads();
    int h = hist[tid];
    scan_[tid] = h;
    __syncthreads();
    for (int d = 1; d < 512; d <<= 1) {
        int t = 0;
        if (tid >= d) t = scan_[tid - d];
        __syncthreads();
        scan_[tid] += t;
        __syncthreads();
    }
    int excl = scan_[tid] - h;
    cur[tid] = excl;
    if (tid < nn) {
        int node = n0 + tid;
        offs[node] = base + excl;
        counts[node] = h;
        dinv[node] = rsqrtf((float)(h + 1));  // +1 self-loop
    }
    __syncthreads();
    for (int i = tid; i < sz; i += 512) {
        unsigned p = se[i];
        int pos = atomicAdd(&cur[p >> 20], 1);
        csr_src[base + pos] = (int)(p & 0xFFFFFu);
    }
}

// xwd = (x @ W1) * dinv[node]
__global__ void gemm1_kernel(const float* __restrict__ x, const float* __restrict__ W1,
                             const float* __restrict__ dinv, float* __restrict__ xwd, int N) {
    __shared__ float ws_[128 * 32];
    for (int i = threadIdx.x; i < 128 * 32; i += blockDim.x) ws_[i] = W1[i];
    __syncthreads();
    int node = blockIdx.x * blockDim.x + threadIdx.x;
    if (node >= N) return;
    float acc[32];
#pragma unroll
    for (int j = 0; j < 32; ++j) acc[j] = 0.0f;
    const float4* xr = (const float4*)(x + (size_t)node * 128);
#pragma unroll 4
    for (int k4 = 0; k4 < 32; ++k4) {
        float4 xv = xr[k4];
        const float* wk = ws_ + k4 * 128;
#pragma unroll
        for (int j4 = 0; j4 < 8; ++j4) {
            float4 w0 = *(const float4*)(wk + j4 * 4);
            float4 w1 = *(const float4*)(wk + 32 + j4 * 4);
            float4 w2 = *(const float4*)(wk + 64 + j4 * 4);
            float4 w3 = *(const float4*)(wk + 96 + j4 * 4);
            acc[j4 * 4 + 0] += xv.x * w0.x + xv.y * w1.x + xv.z * w2.x + xv.w * w3.x;
            acc[j4 * 4 + 1] += xv.x * w0.y + xv.y * w1.y + xv.z * w2.y + xv.w * w3.y;
            acc[j4 * 4 + 2] += xv.x * w0.z + xv.y * w1.z + xv.z * w2.z + xv.w * w3.z;
            acc[j4 * 4 + 3] += xv.x * w0.w + xv.y * w1.w + xv.z * w2.w + xv.w * w3.w;
        }
    }
    float d = dinv[node];
    float4* xp = (float4*)(xwd + (size_t)node * 32);
#pragma unroll
    for (int j4 = 0; j4 < 8; ++j4)
        xp[j4] = make_float4(acc[j4 * 4 + 0] * d, acc[j4 * 4 + 1] * d,
                             acc[j4 * 4 + 2] * d, acc[j4 * 4 + 3] * d);
}

// One wave per node: agg1[d] = dinv[d] * (xwd[d] + sum_{s in in(d)} xwd[s])
__global__ void agg32_kernel(const int* __restrict__ offs, const int* __restrict__ counts,
                             const int* __restrict__ csr_src, const float* __restrict__ dinv,
                             const float* __restrict__ xwd, float* __restrict__ agg, int N) {
    int wave = threadIdx.x >> 6;
    int lane = threadIdx.x & 63;
    int node = blockIdx.x * 4 + wave;
    if (node >= N) return;
    int f = lane & 31;
    int j = lane >> 5;  // 0..1 : two edges in flight per wave
    int off = offs[node];
    int deg = counts[node];
    float acc = (j == 0) ? xwd[(size_t)node * 32 + f] : 0.0f;
    for (int i = j; i < deg; i += 2) {
        int s = csr_src[off + i];
        acc += xwd[(size_t)s * 32 + f];
    }
    acc += __shfl_down(acc, 32, 64);
    if (j == 0) agg[(size_t)node * 32 + f] = acc * dinv[node];
}

// h2wd = (relu(agg1 + b1) @ W2) * dinv[node]
__global__ void gemm2_kernel(const float* __restrict__ agg1, const float* __restrict__ W2,
                             const float* __restrict__ b1, const float* __restrict__ dinv,
                             float* __restrict__ h2wd, int N) {
    __shared__ float ws_[32 * 16];
    __shared__ float bs_[32];
    for (int i = threadIdx.x; i < 32 * 16; i += blockDim.x) ws_[i] = W2[i];
    if (threadIdx.x < 32) bs_[threadIdx.x] = b1[threadIdx.x];
    __syncthreads();
    int node = blockIdx.x * blockDim.x + threadIdx.x;
    if (node >= N) return;
    float h[32];
    const float4* ar = (const float4*)(agg1 + (size_t)node * 32);
#pragma unroll
    for (int k4 = 0; k4 < 8; ++k4) {
        float4 v = ar[k4];
        h[k4 * 4 + 0] = fmaxf(v.x + bs_[k4 * 4 + 0], 0.0f);
        h[k4 * 4 + 1] = fmaxf(v.y + bs_[k4 * 4 + 1], 0.0f);
        h[k4 * 4 + 2] = fmaxf(v.z + bs_[k4 * 4 + 2], 0.0f);
        h[k4 * 4 + 3] = fmaxf(v.w + bs_[k4 * 4 + 3], 0.0f);
    }
    float acc[16];
#pragma unroll
    for (int j = 0; j < 16; ++j) acc[j] = 0.0f;
#pragma unroll
    for (int k = 0; k < 32; ++k) {
        float hv = h[k];
#pragma unroll
        for (int j4 = 0; j4 < 4; ++j4) {
            float4 w = *(const float4*)(ws_ + k * 16 + j4 * 4);
            acc[j4 * 4 + 0] += hv * w.x;
            acc[j4 * 4 + 1] += hv * w.y;
            acc[j4 * 4 + 2] += hv * w.z;
            acc[j4 * 4 + 3] += hv * w.w;
        }
    }
    float d = dinv[node];
    float4* hp = (float4*)(h2wd + (size_t)node * 16);
#pragma unroll
    for (int j4 = 0; j4 < 4; ++j4)
        hp[j4] = make_float4(acc[j4 * 4 + 0] * d, acc[j4 * 4 + 1] * d,
                             acc[j4 * 4 + 2] * d, acc[j4 * 4 + 3] * d);
}

// One wave per node, 16 feats
__global__ void agg16_kernel(const int* __restrict__ offs, const int* __restrict__ counts,
                             const int* __restrict__ csr_src, const float* __restrict__ dinv,
                             const float* __restrict__ h2wd, float* __restrict__ agg, int N) {
    int wave = threadIdx.x >> 6;
    int lane = threadIdx.x & 63;
    int node = blockIdx.x * 4 + wave;
    if (node >= N) return;
    int f = lane & 15;
    int j = lane >> 4;  // 0..3 : four edges in flight per wave
    int off = offs[node];
    int deg = counts[node];
    float acc = (j == 0) ? h2wd[(size_t)node * 16 + f] : 0.0f;
    for (int i = j; i < deg; i += 4) {
        int s = csr_src[off + i];
        acc += h2wd[(size_t)s * 16 + f];
    }
    acc += __shfl_down(acc, 32, 64);
    acc += __shfl_down(acc, 16, 64);
    if (j == 0) agg[(size_t)node * 16 + f] = acc * dinv[node];
}

// out = relu(agg2 + b2) @ Wf + bf
__global__ void final_kernel(const float* __restrict__ agg2, const float* __restrict__ b2,
                             const float* __restrict__ Wf, const float* __restrict__ bf,
                             float* __restrict__ out, int N) {
    int i = blockIdx.x * blockDim.x + threadIdx.x;
    if (i >= N) return;
    const float4* ar = (const float4*)(agg2 + (size_t)i * 16);
    float acc = bf[0];
#pragma unroll
    for (int j4 = 0; j4 < 4; ++j4) {
        float4 v = ar[j4];
        acc += fmaxf(v.x + b2[j4 * 4 + 0], 0.0f) * Wf[j4 * 4 + 0];
        acc += fmaxf(v.y + b2[j4 * 4 + 1], 0.0f) * Wf[j4 * 4 + 1];
        acc += fmaxf(v.z + b2[j4 * 4 + 2], 0.0f) * Wf[j4 * 4 + 2];
        acc += fmaxf(v.w + b2[j4 * 4 + 3], 0.0f) * Wf[j4 * 4 + 3];
    }
    out[i] = acc;
}

extern "C" void kernel_launch(void* const* d_in, const int* in_sizes, int n_in,
                              void* d_out, int out_size, void* d_ws, size_t ws_size,
                              hipStream_t stream) {
    const float* x  = (const float*)d_in[0];
    const int*   ei = (const int*)d_in[1];
    const float* W1 = (const float*)d_in[2];
    const float* b1 = (const float*)d_in[3];
    const float* W2 = (const float*)d_in[4];
    const float* b2 = (const float*)d_in[5];
    const float* Wf = (const float*)d_in[6];
    const float* bf = (const float*)d_in[7];

    int N = in_sizes[0] / 128;
    int E = in_sizes[1] / 2;
    const int* src = ei;       // edge_index[0]
    const int* dst = ei + E;   // edge_index[1]
    int NPB = (N + NBUCK - 1) / NBUCK;  // nodes per bucket (391 for N=100k; <512)

    // Workspace layout
    size_t Np = ((size_t)N + 3) & ~(size_t)3;
    size_t Ep = ((size_t)E + 3) & ~(size_t)3;
    int* wsI      = (int*)d_ws;
    int* counts   = wsI;               // N
    int* offs     = counts + Np;       // N
    int* bcur     = offs + Np;         // 256
    int* bbase    = bcur + NBUCK;      // 256
    int* csr_src  = bbase + NBUCK;     // E
    float* dinv   = (float*)(csr_src + Ep);   // N
    float* xwd    = dinv + Np;         // 32*N
    float* agg1   = xwd + 32 * Np;     // 32*N
    float* h2wd   = agg1 + 32 * Np;    // 16*N
    float* agg2   = h2wd + 16 * Np;    // 16*N
    float* out    = (float*)d_out;
    // Staging (16 MB) aliases agg1+h2wd (19.2 MB): read last in buildB_kernel,
    // overwritten later by agg32_kernel. No lifetime overlap.
    unsigned* staging = (unsigned*)agg1;

    int nbN = (N + TPB - 1) / TPB;
    int nbC = (E + CHUNK - 1) / CHUNK;
    int nbW = (N + 3) / 4;  // one wave (of 4/block) per node

    zero_bcursor_kernel<<<1, NBUCK, 0, stream>>>(bcur);
    binA2_kernel<<<nbC, 256, 0, stream>>>(src, dst, bcur, staging, E, NPB);
    bucket_scan_kernel<<<1, NBUCK, 0, stream>>>(bcur, bbase);
    buildB_kernel<<<NBUCK, 512, 0, stream>>>(bcur, bbase, staging, offs, counts,
                                             dinv, csr_src, N, NPB);
    gemm1_kernel<<<nbN, TPB, 0, stream>>>(x, W1, dinv, xwd, N);
    agg32_kernel<<<nbW, TPB, 0, stream>>>(offs, counts, csr_src, dinv, xwd, agg1, N);
    gemm2_kernel<<<nbN, TPB, 0, stream>>>(agg1, W2, b1, dinv, h2wd, N);
    agg16_kernel<<<nbW, TPB, 0, stream>>>(offs, counts, csr_src, dinv, h2wd, agg2, N);
    final_kernel<<<nbN, TPB, 0, stream>>>(agg2, b2, Wf, bf, out, N);
}

// Round 6
// 301.915 us; speedup vs baseline: 6.1179x; 1.4099x over previous
//
#include <hip/hip_runtime.h>

// GCN forward via two-level CSR build + gather aggregation (no float atomics).
//   Phase A (binA2): per-block LDS radix partition of 8192 edges into 256
//     dst-range buckets; one global atomicAdd per (block,bucket).
//   Phase B (buildB): one block per bucket: LDS histogram+scan -> counts/offs/
//     dinv + CSR placement into contiguous span.
//   gemm1: xwd = (x@W1)*dinv;  agg1[d] = dinv[d]*(xwd[d]+sum_in xwd[s]);
//   gemm2: h2wd = (relu(agg1+b1)@W2)*dinv;  agg2 likewise;  head.
//   agg kernels: float4 lane geometry -> 8 (resp 16) edge-gathers in flight
//   per wave to beat the ~500-cyc gather latency (round-5 MLP bottleneck).

#define TPB 256
#define NBUCK 256
#define BCAP 16384   // bucket capacity; mean ~12512 -> large margin
#define CHUNK 8192   // edges per binA2 block

__global__ void zero_bcursor_kernel(int* __restrict__ bcur) {
    bcur[threadIdx.x] = 0;
}

// Phase A: block-local radix partition, then bulk append to global staging.
__global__ __launch_bounds__(256) void binA2_kernel(
        const int* __restrict__ src, const int* __restrict__ dst,
        int* __restrict__ bcur, unsigned* __restrict__ staging, int E, int NPB) {
    __shared__ unsigned packed[CHUNK];
    __shared__ unsigned char buckb[CHUNK];
    __shared__ int hist[NBUCK];
    __shared__ int scan_[NBUCK];
    __shared__ int lstart[NBUCK];
    __shared__ int lcur[NBUCK];
    __shared__ int gbase[NBUCK];
    int tid = threadIdx.x;
    int start = blockIdx.x * CHUNK;
    int sz = min(CHUNK, E - start);

    hist[tid] = 0;
    __syncthreads();
    for (int i = tid; i < sz; i += 256) {
        unsigned d = (unsigned)dst[start + i];
        atomicAdd(&hist[d / (unsigned)NPB], 1);
    }
    __syncthreads();
    int v = hist[tid];
    scan_[tid] = v;
    __syncthreads();
    for (int dd = 1; dd < NBUCK; dd <<= 1) {
        int t = 0;
        if (tid >= dd) t = scan_[tid - dd];
        __syncthreads();
        scan_[tid] += t;
        __syncthreads();
    }
    lstart[tid] = scan_[tid] - v;
    lcur[tid] = 0;
    gbase[tid] = atomicAdd(&bcur[tid], v);  // reserve once per (block,bucket)
    __syncthreads();
    for (int i = tid; i < sz; i += 256) {
        unsigned d = (unsigned)dst[start + i];
        unsigned s = (unsigned)src[start + i];
        unsigned b = d / (unsigned)NPB;
        unsigned loc = d - b * (unsigned)NPB;
        int pos = atomicAdd(&lcur[b], 1);
        int si = lstart[b] + pos;
        packed[si] = (loc << 20) | s;
        buckb[si] = (unsigned char)b;
    }
    __syncthreads();
    for (int i = tid; i < sz; i += 256) {
        unsigned b = buckb[i];
        int dsti = gbase[b] + (i - lstart[b]);
        if (dsti < BCAP)
            staging[(size_t)b * BCAP + dsti] = packed[i];
    }
}

// Exclusive scan of clamped bucket sizes -> bbase (single block of 256)
__global__ void bucket_scan_kernel(const int* __restrict__ bcur, int* __restrict__ bbase) {
    __shared__ int s[NBUCK];
    int tid = threadIdx.x;
    int v = min(bcur[tid], BCAP);
    s[tid] = v;
    __syncthreads();
    for (int d = 1; d < NBUCK; d <<= 1) {
        int t = 0;
        if (tid >= d) t = s[tid - d];
        __syncthreads();
        s[tid] += t;
        __syncthreads();
    }
    bbase[tid] = s[tid] - v;  // exclusive
}

// Phase B: one block (512 thr) per bucket. Histogram + scan + CSR placement.
__global__ void buildB_kernel(const int* __restrict__ bcur, const int* __restrict__ bbase,
                              const unsigned* __restrict__ staging,
                              int* __restrict__ offs, int* __restrict__ counts,
                              float* __restrict__ dinv, int* __restrict__ csr_src,
                              int N, int NPB) {
    __shared__ int hist[512];
    __shared__ int scan_[512];
    __shared__ int cur[512];
    int b = blockIdx.x;
    int tid = threadIdx.x;
    int sz = min(bcur[b], BCAP);
    int base = bbase[b];
    int n0 = b * NPB;
    int nn = min(NPB, N - n0);
    const unsigned* se = staging + (size_t)b * BCAP;

    hist[tid] = 0;
    __syncthreads();
    for (int i = tid; i < sz; i += 512)
        atomicAdd(&hist[se[i] >> 20], 1);
    __syncthreads();
    int h = hist[tid];
    scan_[tid] = h;
    __syncthreads();
    for (int d = 1; d < 512; d <<= 1) {
        int t = 0;
        if (tid >= d) t = scan_[tid - d];
        __syncthreads();
        scan_[tid] += t;
        __syncthreads();
    }
    int excl = scan_[tid] - h;
    cur[tid] = excl;
    if (tid < nn) {
        int node = n0 + tid;
        offs[node] = base + excl;
        counts[node] = h;
        dinv[node] = rsqrtf((float)(h + 1));  // +1 self-loop
    }
    __syncthreads();
    for (int i = tid; i < sz; i += 512) {
        unsigned p = se[i];
        int pos = atomicAdd(&cur[p >> 20], 1);
        csr_src[base + pos] = (int)(p & 0xFFFFFu);
    }
}

// xwd = (x @ W1) * dinv[node]
__global__ void gemm1_kernel(const float* __restrict__ x, const float* __restrict__ W1,
                             const float* __restrict__ dinv, float* __restrict__ xwd, int N) {
    __shared__ float ws_[128 * 32];
    for (int i = threadIdx.x; i < 128 * 32; i += blockDim.x) ws_[i] = W1[i];
    __syncthreads();
    int node = blockIdx.x * blockDim.x + threadIdx.x;
    if (node >= N) return;
    float acc[32];
#pragma unroll
    for (int j = 0; j < 32; ++j) acc[j] = 0.0f;
    const float4* xr = (const float4*)(x + (size_t)node * 128);
#pragma unroll 4
    for (int k4 = 0; k4 < 32; ++k4) {
        float4 xv = xr[k4];
        const float* wk = ws_ + k4 * 128;
#pragma unroll
        for (int j4 = 0; j4 < 8; ++j4) {
            float4 w0 = *(const float4*)(wk + j4 * 4);
            float4 w1 = *(const float4*)(wk + 32 + j4 * 4);
            float4 w2 = *(const float4*)(wk + 64 + j4 * 4);
            float4 w3 = *(const float4*)(wk + 96 + j4 * 4);
            acc[j4 * 4 + 0] += xv.x * w0.x + xv.y * w1.x + xv.z * w2.x + xv.w * w3.x;
            acc[j4 * 4 + 1] += xv.x * w0.y + xv.y * w1.y + xv.z * w2.y + xv.w * w3.y;
            acc[j4 * 4 + 2] += xv.x * w0.z + xv.y * w1.z + xv.z * w2.z + xv.w * w3.z;
            acc[j4 * 4 + 3] += xv.x * w0.w + xv.y * w1.w + xv.z * w2.w + xv.w * w3.w;
        }
    }
    float d = dinv[node];
    float4* xp = (float4*)(xwd + (size_t)node * 32);
#pragma unroll
    for (int j4 = 0; j4 < 8; ++j4)
        xp[j4] = make_float4(acc[j4 * 4 + 0] * d, acc[j4 * 4 + 1] * d,
                             acc[j4 * 4 + 2] * d, acc[j4 * 4 + 3] * d);
}

// One wave per node, float4 lanes: q=lane&7 covers the 32-float row,
// g=lane>>3 gives 8 edge-gathers in flight.
__global__ void agg32_kernel(const int* __restrict__ offs, const int* __restrict__ counts,
                             const int* __restrict__ csr_src, const float* __restrict__ dinv,
                             const float* __restrict__ xwd, float* __restrict__ agg, int N) {
    int wave = threadIdx.x >> 6;
    int lane = threadIdx.x & 63;
    int node = blockIdx.x * 4 + wave;
    if (node >= N) return;
    int q = lane & 7;       // float4 slot within row
    int g = lane >> 3;      // edge slot: 8 in flight
    int off = offs[node];
    int deg = counts[node];
    float4 acc = make_float4(0.f, 0.f, 0.f, 0.f);
    if (g == 0) acc = *(const float4*)(xwd + (size_t)node * 32 + q * 4);
    for (int i = g; i < deg; i += 8) {
        int s = csr_src[off + i];
        float4 v = *(const float4*)(xwd + (size_t)s * 32 + q * 4);
        acc.x += v.x; acc.y += v.y; acc.z += v.z; acc.w += v.w;
    }
#pragma unroll
    for (int d = 32; d >= 8; d >>= 1) {
        acc.x += __shfl_down(acc.x, d, 64);
        acc.y += __shfl_down(acc.y, d, 64);
        acc.z += __shfl_down(acc.z, d, 64);
        acc.w += __shfl_down(acc.w, d, 64);
    }
    if (g == 0) {
        float dv = dinv[node];
        *(float4*)(agg + (size_t)node * 32 + q * 4) =
            make_float4(acc.x * dv, acc.y * dv, acc.z * dv, acc.w * dv);
    }
}

// h2wd = (relu(agg1 + b1) @ W2) * dinv[node]
__global__ void gemm2_kernel(const float* __restrict__ agg1, const float* __restrict__ W2,
                             const float* __restrict__ b1, const float* __restrict__ dinv,
                             float* __restrict__ h2wd, int N) {
    __shared__ float ws_[32 * 16];
    __shared__ float bs_[32];
    for (int i = threadIdx.x; i < 32 * 16; i += blockDim.x) ws_[i] = W2[i];
    if (threadIdx.x < 32) bs_[threadIdx.x] = b1[threadIdx.x];
    __syncthreads();
    int node = blockIdx.x * blockDim.x + threadIdx.x;
    if (node >= N) return;
    float h[32];
    const float4* ar = (const float4*)(agg1 + (size_t)node * 32);
#pragma unroll
    for (int k4 = 0; k4 < 8; ++k4) {
        float4 v = ar[k4];
        h[k4 * 4 + 0] = fmaxf(v.x + bs_[k4 * 4 + 0], 0.0f);
        h[k4 * 4 + 1] = fmaxf(v.y + bs_[k4 * 4 + 1], 0.0f);
        h[k4 * 4 + 2] = fmaxf(v.z + bs_[k4 * 4 + 2], 0.0f);
        h[k4 * 4 + 3] = fmaxf(v.w + bs_[k4 * 4 + 3], 0.0f);
    }
    float acc[16];
#pragma unroll
    for (int j = 0; j < 16; ++j) acc[j] = 0.0f;
#pragma unroll
    for (int k = 0; k < 32; ++k) {
        float hv = h[k];
#pragma unroll
        for (int j4 = 0; j4 < 4; ++j4) {
            float4 w = *(const float4*)(ws_ + k * 16 + j4 * 4);
            acc[j4 * 4 + 0] += hv * w.x;
            acc[j4 * 4 + 1] += hv * w.y;
            acc[j4 * 4 + 2] += hv * w.z;
            acc[j4 * 4 + 3] += hv * w.w;
        }
    }
    float d = dinv[node];
    float4* hp = (float4*)(h2wd + (size_t)node * 16);
#pragma unroll
    for (int j4 = 0; j4 < 4; ++j4)
        hp[j4] = make_float4(acc[j4 * 4 + 0] * d, acc[j4 * 4 + 1] * d,
                             acc[j4 * 4 + 2] * d, acc[j4 * 4 + 3] * d);
}

// One wave per node, 16 feats: q=lane&3, g=lane>>2 -> 16 edges in flight.
__global__ void agg16_kernel(const int* __restrict__ offs, const int* __restrict__ counts,
                             const int* __restrict__ csr_src, const float* __restrict__ dinv,
                             const float* __restrict__ h2wd, float* __restrict__ agg, int N) {
    int wave = threadIdx.x >> 6;
    int lane = threadIdx.x & 63;
    int node = blockIdx.x * 4 + wave;
    if (node >= N) return;
    int q = lane & 3;       // float4 slot within 16-float row
    int g = lane >> 2;      // edge slot: 16 in flight
    int off = offs[node];
    int deg = counts[node];
    float4 acc = make_float4(0.f, 0.f, 0.f, 0.f);
    if (g == 0) acc = *(const float4*)(h2wd + (size_t)node * 16 + q * 4);
    for (int i = g; i < deg; i += 16) {
        int s = csr_src[off + i];
        float4 v = *(const float4*)(h2wd + (size_t)s * 16 + q * 4);
        acc.x += v.x; acc.y += v.y; acc.z += v.z; acc.w += v.w;
    }
#pragma unroll
    for (int d = 32; d >= 4; d >>= 1) {
        acc.x += __shfl_down(acc.x, d, 64);
        acc.y += __shfl_down(acc.y, d, 64);
        acc.z += __shfl_down(acc.z, d, 64);
        acc.w += __shfl_down(acc.w, d, 64);
    }
    if (g == 0) {
        float dv = dinv[node];
        *(float4*)(agg + (size_t)node * 16 + q * 4) =
            make_float4(acc.x * dv, acc.y * dv, acc.z * dv, acc.w * dv);
    }
}

// out = relu(agg2 + b2) @ Wf + bf
__global__ void final_kernel(const float* __restrict__ agg2, const float* __restrict__ b2,
                             const float* __restrict__ Wf, const float* __restrict__ bf,
                             float* __restrict__ out, int N) {
    int i = blockIdx.x * blockDim.x + threadIdx.x;
    if (i >= N) return;
    const float4* ar = (const float4*)(agg2 + (size_t)i * 16);
    float acc = bf[0];
#pragma unroll
    for (int j4 = 0; j4 < 4; ++j4) {
        float4 v = ar[j4];
        acc += fmaxf(v.x + b2[j4 * 4 + 0], 0.0f) * Wf[j4 * 4 + 0];
        acc += fmaxf(v.y + b2[j4 * 4 + 1], 0.0f) * Wf[j4 * 4 + 1];
        acc += fmaxf(v.z + b2[j4 * 4 + 2], 0.0f) * Wf[j4 * 4 + 2];
        acc += fmaxf(v.w + b2[j4 * 4 + 3], 0.0f) * Wf[j4 * 4 + 3];
    }
    out[i] = acc;
}

extern "C" void kernel_launch(void* const* d_in, const int* in_sizes, int n_in,
                              void* d_out, int out_size, void* d_ws, size_t ws_size,
                              hipStream_t stream) {
    const float* x  = (const float*)d_in[0];
    const int*   ei = (const int*)d_in[1];
    const float* W1 = (const float*)d_in[2];
    const float* b1 = (const float*)d_in[3];
    const float* W2 = (const float*)d_in[4];
    const float* b2 = (const float*)d_in[5];
    const float* Wf = (const float*)d_in[6];
    const float* bf = (const float*)d_in[7];

    int N = in_sizes[0] / 128;
    int E = in_sizes[1] / 2;
    const int* src = ei;       // edge_index[0]
    const int* dst = ei + E;   // edge_index[1]
    int NPB = (N + NBUCK - 1) / NBUCK;  // nodes per bucket (391 for N=100k; <512)

    // Workspace layout
    size_t Np = ((size_t)N + 3) & ~(size_t)3;
    size_t Ep = ((size_t)E + 3) & ~(size_t)3;
    int* wsI      = (int*)d_ws;
    int* counts   = wsI;               // N
    int* offs     = counts + Np;       // N
    int* bcur     = offs + Np;         // 256
    int* bbase    = bcur + NBUCK;      // 256
    int* csr_src  = bbase + NBUCK;     // E
    float* dinv   = (float*)(csr_src + Ep);   // N
    float* xwd    = dinv + Np;         // 32*N
    float* agg1   = xwd + 32 * Np;     // 32*N
    float* h2wd   = agg1 + 32 * Np;    // 16*N
    float* agg2   = h2wd + 16 * Np;    // 16*N
    float* out    = (float*)d_out;
    // Staging (16 MB) aliases agg1+h2wd (19.2 MB): read last in buildB_kernel,
    // overwritten later by agg32_kernel. No lifetime overlap.
    unsigned* staging = (unsigned*)agg1;

    int nbN = (N + TPB - 1) / TPB;
    int nbC = (E + CHUNK - 1) / CHUNK;
    int nbW = (N + 3) / 4;  // one wave (of 4/block) per node

    zero_bcursor_kernel<<<1, NBUCK, 0, stream>>>(bcur);
    binA2_kernel<<<nbC, 256, 0, stream>>>(src, dst, bcur, staging, E, NPB);
    bucket_scan_kernel<<<1, NBUCK, 0, stream>>>(bcur, bbase);
    buildB_kernel<<<NBUCK, 512, 0, stream>>>(bcur, bbase, staging, offs, counts,
                                             dinv, csr_src, N, NPB);
    gemm1_kernel<<<nbN, TPB, 0, stream>>>(x, W1, dinv, xwd, N);
    agg32_kernel<<<nbW, TPB, 0, stream>>>(offs, counts, csr_src, dinv, xwd, agg1, N);
    gemm2_kernel<<<nbN, TPB, 0, stream>>>(agg1, W2, b1, dinv, h2wd, N);
    agg16_kernel<<<nbW, TPB, 0, stream>>>(offs, counts, csr_src, dinv, h2wd, agg2, N);
    final_kernel<<<nbN, TPB, 0, stream>>>(agg2, b2, Wf, bf, out, N);
}